// Round 11
// baseline (519.877 us; speedup 1.0000x reference)
//
#include <hip/hip_runtime.h>
#include <math.h>

#define B_TOTAL 16384
#define T_STEPS 20
#define NGRP    1024            // B_TOTAL/16 batch groups per sensor

#define LOG2E    1.44269504088896f
#define TWOLOG2E 2.88539008177793f

typedef __attribute__((ext_vector_type(8))) __bf16 bf16x8;
typedef __attribute__((ext_vector_type(4))) float f32x4;

// ---------------------------------------------------------------------------
// Activations on pre-scaled inputs (z already multiplied by log2e; 2log2e for
// the g-gate row): every exp is a bare v_exp_f32, neg via source modifier.
__device__ __forceinline__ float sig2(float xp) {          // sigmoid(z)
    return __builtin_amdgcn_rcpf(1.0f + __builtin_exp2f(-xp));
}
__device__ __forceinline__ float tanh2pre(float xp) {      // tanh(z), xp=2z*log2e
    return fmaf(-2.0f, __builtin_amdgcn_rcpf(__builtin_exp2f(xp) + 1.0f), 1.0f);
}
__device__ __forceinline__ float tanh2(float c) {          // tanh(c), c unscaled
    return fmaf(-2.0f,
                __builtin_amdgcn_rcpf(__builtin_exp2f(c * TWOLOG2E) + 1.0f), 1.0f);
}

// Truncation-based Dekker split: hi = top-16-bits of x, lo = top-16 of (x-hi).
__device__ __forceinline__ __bf16 bf16_bits(unsigned short s) {
    __bf16 r; __builtin_memcpy(&r, &s, 2); return r;
}
__device__ __forceinline__ void split_trunc(float x, __bf16& hi, __bf16& lo) {
    unsigned u = __float_as_uint(x);
    hi = bf16_bits((unsigned short)(u >> 16));
    float l = x - __uint_as_float(u & 0xFFFF0000u);
    lo = bf16_bits((unsigned short)(__float_as_uint(l) >> 16));
}

// ---------------------------------------------------------------------------
// Fused 5-layer LSTM via bf16 MFMA, hi/lo compensated — R6 step structure
// (measured local optimum; R7/R8 micro-variants regressed) with:
//  - log2e pre-scaled weights/biases -> bare exp2 activations (R8-verified math)
//  - fc1-partial tail (B straight from LDS, A from pre-split W1, unroll 2)
//  - fused finisher: 2nd block of each group (device atomic) sums partials,
//    bias+ReLU+fc2, writes out. Deletes the fc_finish launch + 16 MB re-read.
__global__ __launch_bounds__(256, 4)
void lstm5_mfma(const float* __restrict__ accel, const float* __restrict__ gyro,
                const float* __restrict__ aWih0, const float* __restrict__ aWihR,
                const float* __restrict__ aWhh,  const float* __restrict__ aBih,
                const float* __restrict__ aBhh,
                const float* __restrict__ gWih0, const float* __restrict__ gWihR,
                const float* __restrict__ gWhh,  const float* __restrict__ gBih,
                const float* __restrict__ gBhh,
                const __bf16* __restrict__ w1ah, const __bf16* __restrict__ w1al,
                float* __restrict__ Zpart /* [2][NGRP][8][16][16] */,
                int* __restrict__ cnt /* [NGRP], zeroed by w1_prep */,
                const float* __restrict__ fc1_b, const float* __restrict__ fc2_w,
                const float* __restrict__ fc2_b, float* __restrict__ out) {
    const int tid  = threadIdx.x;
    const int w    = tid >> 6;        // wave 0..3
    const int lane = tid & 63;
    const int e    = lane & 15;       // elem (B-frag col / C col)
    const int quad = lane >> 4;       // 0..3
    const int sensor = blockIdx.y;
    const int bbase  = blockIdx.x * 16;

    const float* xin  = sensor ? gyro  : accel;
    const float* Wih0 = sensor ? gWih0 : aWih0;
    const float* WihR = sensor ? gWihR : aWihR;
    const float* Whh  = sensor ? gWhh  : aWhh;
    const float* Bih  = sensor ? gBih  : aBih;
    const float* Bhh  = sensor ? gBhh  : aBhh;

    __shared__ __align__(16) __bf16 shi[20 * 512];    // [t][chunk][e][j]
    __shared__ __align__(16) __bf16 slo[20 * 512];
    __shared__ int sflag;

    const int ug0 = w * 8 + quad;        // tile 0 unit
    const int ug1 = w * 8 + 4 + quad;    // tile 1 unit

    const int m_row   = lane & 15;
    const int orow_t0 = (m_row & 3) * 32 + (w * 8 + (m_row >> 2));
    const int orow_t1 = (m_row & 3) * 32 + (w * 8 + 4 + (m_row >> 2));
    const float sA = ((m_row & 3) == 2) ? TWOLOG2E : LOG2E;   // g-gate rows 2x

    bf16x8 wih_h0, wih_l0, wih_h1, wih_l1;
    bf16x8 whh_h0, whh_l0, whh_h1, whh_l1;
    f32x4  bias0v, bias1v;
    float  c0 = 0.f, c1 = 0.f;

#define LOAD_FRAG(Wsrc, orow, fh, fl)                         \
    {                                                         \
        const float* p_ = (Wsrc) + (orow) * 32 + quad * 8;    \
        _Pragma("unroll")                                     \
        for (int jj = 0; jj < 8; ++jj) {                      \
            __bf16 h_, l_;                                    \
            split_trunc(p_[jj] * sA, h_, l_);                 \
            (fh)[jj] = h_;  (fl)[jj] = l_;                    \
        }                                                     \
    }

#define LOAD_BIAS(l)                                                        \
    {                                                                       \
        _Pragma("unroll")                                                   \
        for (int r = 0; r < 4; ++r) {                                       \
            float sc = (r == 2) ? TWOLOG2E : LOG2E;                         \
            bias0v[r] = (Bih[(l) * 128 + r * 32 + ug0] + Bhh[(l) * 128 + r * 32 + ug0]) * sc; \
            bias1v[r] = (Bih[(l) * 128 + r * 32 + ug1] + Bhh[(l) * 128 + r * 32 + ug1]) * sc; \
        }                                                                   \
    }

#define ACT_STORE(t)                                                        \
    {                                                                       \
        float i0 = sig2(acc0[0]), f0 = sig2(acc0[1]);                       \
        float g0 = tanh2pre(acc0[2]), o0 = sig2(acc0[3]);                   \
        c0 = f0 * c0 + i0 * g0;                                             \
        float h0 = o0 * tanh2(c0);                                          \
        float i1 = sig2(acc1[0]), f1 = sig2(acc1[1]);                       \
        float g1 = tanh2pre(acc1[2]), o1 = sig2(acc1[3]);                   \
        c1 = f1 * c1 + i1 * g1;                                             \
        float h1 = o1 * tanh2(c1);                                          \
        __syncthreads();  /* all waves done reading shi/slo[t] */           \
        int i0x = (t) * 512 + w * 128 + e * 8 + quad;                       \
        int i1x = i0x + 4;                                                  \
        __bf16 hh_, ll_;                                                    \
        split_trunc(h0, hh_, ll_);  shi[i0x] = hh_;  slo[i0x] = ll_;        \
        split_trunc(h1, hh_, ll_);  shi[i1x] = hh_;  slo[i1x] = ll_;        \
        __syncthreads();  /* writes visible before next step's reads */     \
    }

    // ================= layer 0 (ih is K=3, done in VALU) =================
    {
        LOAD_FRAG(Whh, orow_t0, whh_h0, whh_l0);
        LOAD_FRAG(Whh, orow_t1, whh_h1, whh_l1);
        LOAD_BIAS(0);
        float w0reg[2][4][3];
#pragma unroll
        for (int r = 0; r < 4; ++r) {
            float sc = (r == 2) ? TWOLOG2E : LOG2E;
#pragma unroll
            for (int k = 0; k < 3; ++k) {
                w0reg[0][r][k] = Wih0[(r * 32 + ug0) * 3 + k] * sc;
                w0reg[1][r][k] = Wih0[(r * 32 + ug1) * 3 + k] * sc;
            }
        }
        const float* xrow = xin + (size_t)(bbase + e) * (T_STEPS * 3);

        for (int t = 0; t < T_STEPS; ++t) {
            float x0 = xrow[t * 3 + 0];
            float x1 = xrow[t * 3 + 1];
            float x2 = xrow[t * 3 + 2];
            f32x4 acc0 = bias0v;
            f32x4 acc1 = bias1v;
#pragma unroll
            for (int r = 0; r < 4; ++r) {
                acc0[r] = fmaf(w0reg[0][r][0], x0,
                          fmaf(w0reg[0][r][1], x1,
                          fmaf(w0reg[0][r][2], x2, acc0[r])));
                acc1[r] = fmaf(w0reg[1][r][0], x0,
                          fmaf(w0reg[1][r][1], x1,
                          fmaf(w0reg[1][r][2], x2, acc1[r])));
            }
            if (t > 0) {
                int rb = (t - 1) * 512 + quad * 128 + e * 8;
                bf16x8 bh = *(const bf16x8*)&shi[rb];
                bf16x8 bl = *(const bf16x8*)&slo[rb];
                acc0 = __builtin_amdgcn_mfma_f32_16x16x32_bf16(whh_h0, bh, acc0, 0, 0, 0);
                acc0 = __builtin_amdgcn_mfma_f32_16x16x32_bf16(whh_h0, bl, acc0, 0, 0, 0);
                acc0 = __builtin_amdgcn_mfma_f32_16x16x32_bf16(whh_l0, bh, acc0, 0, 0, 0);
                acc1 = __builtin_amdgcn_mfma_f32_16x16x32_bf16(whh_h1, bh, acc1, 0, 0, 0);
                acc1 = __builtin_amdgcn_mfma_f32_16x16x32_bf16(whh_h1, bl, acc1, 0, 0, 0);
                acc1 = __builtin_amdgcn_mfma_f32_16x16x32_bf16(whh_l1, bh, acc1, 0, 0, 0);
            }
            ACT_STORE(t);
        }
    }

    // ================= layers 1..4 (both projections via MFMA) ===========
    for (int l = 1; l < 5; ++l) {
        const float* Wi = WihR + (l - 1) * 4096;
        const float* Wh = Whh + l * 4096;
        LOAD_FRAG(Wi, orow_t0, wih_h0, wih_l0);
        LOAD_FRAG(Wi, orow_t1, wih_h1, wih_l1);
        LOAD_FRAG(Wh, orow_t0, whh_h0, whh_l0);
        LOAD_FRAG(Wh, orow_t1, whh_h1, whh_l1);
        LOAD_BIAS(l);
        c0 = 0.f; c1 = 0.f;

        for (int t = 0; t < T_STEPS; ++t) {
            f32x4 acc0, acc1;
            {   // ih: x = h_{l-1}(t); bias rides in as C of first MFMA
                int rb = t * 512 + quad * 128 + e * 8;
                bf16x8 bh = *(const bf16x8*)&shi[rb];
                bf16x8 bl = *(const bf16x8*)&slo[rb];
                acc0 = __builtin_amdgcn_mfma_f32_16x16x32_bf16(wih_h0, bh, bias0v, 0, 0, 0);
                acc0 = __builtin_amdgcn_mfma_f32_16x16x32_bf16(wih_h0, bl, acc0, 0, 0, 0);
                acc0 = __builtin_amdgcn_mfma_f32_16x16x32_bf16(wih_l0, bh, acc0, 0, 0, 0);
                acc1 = __builtin_amdgcn_mfma_f32_16x16x32_bf16(wih_h1, bh, bias1v, 0, 0, 0);
                acc1 = __builtin_amdgcn_mfma_f32_16x16x32_bf16(wih_h1, bl, acc1, 0, 0, 0);
                acc1 = __builtin_amdgcn_mfma_f32_16x16x32_bf16(wih_l1, bh, acc1, 0, 0, 0);
            }
            if (t > 0) {
                int rb = (t - 1) * 512 + quad * 128 + e * 8;
                bf16x8 bh = *(const bf16x8*)&shi[rb];
                bf16x8 bl = *(const bf16x8*)&slo[rb];
                acc0 = __builtin_amdgcn_mfma_f32_16x16x32_bf16(whh_h0, bh, acc0, 0, 0, 0);
                acc0 = __builtin_amdgcn_mfma_f32_16x16x32_bf16(whh_h0, bl, acc0, 0, 0, 0);
                acc0 = __builtin_amdgcn_mfma_f32_16x16x32_bf16(whh_l0, bh, acc0, 0, 0, 0);
                acc1 = __builtin_amdgcn_mfma_f32_16x16x32_bf16(whh_h1, bh, acc1, 0, 0, 0);
                acc1 = __builtin_amdgcn_mfma_f32_16x16x32_bf16(whh_h1, bl, acc1, 0, 0, 0);
                acc1 = __builtin_amdgcn_mfma_f32_16x16x32_bf16(whh_l1, bh, acc1, 0, 0, 0);
            }
            ACT_STORE(t);
        }
    }
    __syncthreads();

    // ---- fc1-partial tail: Z[sensor-half] = W1[:, half] · X -------------
    {
        f32x4 zacc0 = (f32x4){0.f, 0.f, 0.f, 0.f};
        f32x4 zacc1 = (f32x4){0.f, 0.f, 0.f, 0.f};
        const int mt0 = w * 2, mt1 = w * 2 + 1;
#pragma unroll 2
        for (int t = 0; t < T_STEPS; ++t) {
            int rb = t * 512 + quad * 128 + e * 8;
            bf16x8 bh = *(const bf16x8*)&shi[rb];
            bf16x8 bl = *(const bf16x8*)&slo[rb];
            int ks = sensor * 20 + t;
            size_t ab0 = ((size_t)((mt0 * 40 + ks) * 64 + lane)) * 8;
            size_t ab1 = ((size_t)((mt1 * 40 + ks) * 64 + lane)) * 8;
            bf16x8 ah0 = *(const bf16x8*)(w1ah + ab0);
            bf16x8 al0 = *(const bf16x8*)(w1al + ab0);
            bf16x8 ah1 = *(const bf16x8*)(w1ah + ab1);
            bf16x8 al1 = *(const bf16x8*)(w1al + ab1);
            zacc0 = __builtin_amdgcn_mfma_f32_16x16x32_bf16(ah0, bh, zacc0, 0, 0, 0);
            zacc0 = __builtin_amdgcn_mfma_f32_16x16x32_bf16(ah0, bl, zacc0, 0, 0, 0);
            zacc0 = __builtin_amdgcn_mfma_f32_16x16x32_bf16(al0, bh, zacc0, 0, 0, 0);
            zacc1 = __builtin_amdgcn_mfma_f32_16x16x32_bf16(ah1, bh, zacc1, 0, 0, 0);
            zacc1 = __builtin_amdgcn_mfma_f32_16x16x32_bf16(ah1, bl, zacc1, 0, 0, 0);
            zacc1 = __builtin_amdgcn_mfma_f32_16x16x32_bf16(al1, bh, zacc1, 0, 0, 0);
        }
        float* zp = Zpart + ((size_t)(sensor * NGRP + blockIdx.x)) * 2048;
#pragma unroll
        for (int r = 0; r < 4; ++r) {
            zp[mt0 * 256 + (quad * 4 + r) * 16 + e] = zacc0[r];
            zp[mt1 * 256 + (quad * 4 + r) * 16 + e] = zacc1[r];
        }
    }

    // ---- fused finisher: 2nd arriving block of this group does fc2 ------
    __threadfence();                 // release Zpart writes (device scope)
    __syncthreads();                 // all threads' fences done
    if (tid == 0) sflag = atomicAdd(&cnt[blockIdx.x], 1);
    __syncthreads();                 // broadcast sflag (block-uniform branch)
    if (sflag == 1) {
        __threadfence();             // acquire the other block's Zpart
        float* sp = (float*)shi;     // reuse LDS as [16*16][5] scratch
        const float* z0 = Zpart + (size_t)blockIdx.x * 2048;
        const float* z1 = Zpart + (size_t)(NGRP + blockIdx.x) * 2048;
        const int e2 = tid & 15, rt = tid >> 4;
        float p[5] = {0.f, 0.f, 0.f, 0.f, 0.f};
#pragma unroll
        for (int rr = 0; rr < 8; ++rr) {
            int row = rt * 8 + rr;
            int zi  = (row >> 4) * 256 + (row & 15) * 16 + e2;
            float v = fmaxf(z0[zi] + z1[zi] + fc1_b[row], 0.f);
#pragma unroll
            for (int n = 0; n < 5; ++n) p[n] = fmaf(v, fc2_w[n * 128 + row], p[n]);
        }
#pragma unroll
        for (int n = 0; n < 5; ++n) sp[(rt * 16 + e2) * 5 + n] = p[n];
        __syncthreads();
        if (tid < 80) {
            int col = tid / 5, n = tid - col * 5;
            float s = fc2_b[n];
#pragma unroll
            for (int k = 0; k < 16; ++k) s += sp[(k * 16 + col) * 5 + n];
            out[(size_t)(blockIdx.x * 16 + col) * 5 + n] = s;
        }
    }
#undef LOAD_FRAG
#undef LOAD_BIAS
#undef ACT_STORE
}

// ---------------------------------------------------------------------------
// fc1_w [128][1280] -> MFMA A-frag hi/lo arrays: [mt 0..7][ks 0..39][lane][8].
// Also zeroes the per-group atomic counters (stream-ordered before lstm).
// NOTE: fc weights are NOT log2e-scaled.
__global__ void w1_prep(const float* __restrict__ w1,
                        __bf16* __restrict__ w1ah, __bf16* __restrict__ w1al,
                        int* __restrict__ cnt) {
    int t = blockIdx.x * blockDim.x + threadIdx.x;     // 8*40*64 = 20480
    if (t < NGRP) cnt[t] = 0;
    if (t >= 20480) return;
    int lane = t & 63;
    int ks   = (t >> 6) % 40;
    int mt   = t / (64 * 40);
    int row  = mt * 16 + (lane & 15);
    int col0 = ks * 32 + (lane >> 4) * 8;
    const float* src = w1 + row * 1280 + col0;
#pragma unroll
    for (int j = 0; j < 8; ++j) {
        __bf16 h_, l_;
        split_trunc(src[j], h_, l_);
        w1ah[t * 8 + j] = h_;
        w1al[t * 8 + j] = l_;
    }
}

// ---------------------------------------------------------------------------
extern "C" void kernel_launch(void* const* d_in, const int* in_sizes, int n_in,
                              void* d_out, int out_size, void* d_ws, size_t ws_size,
                              hipStream_t stream) {
    const float* accel  = (const float*)d_in[0];
    const float* gyro   = (const float*)d_in[1];
    const float* aWih0  = (const float*)d_in[2];
    const float* aWihR  = (const float*)d_in[3];
    const float* aWhh   = (const float*)d_in[4];
    const float* aBih   = (const float*)d_in[5];
    const float* aBhh   = (const float*)d_in[6];
    const float* gWih0  = (const float*)d_in[7];
    const float* gWihR  = (const float*)d_in[8];
    const float* gWhh   = (const float*)d_in[9];
    const float* gBih   = (const float*)d_in[10];
    const float* gBhh   = (const float*)d_in[11];
    const float* fc1_w  = (const float*)d_in[12];
    const float* fc1_b  = (const float*)d_in[13];
    const float* fc2_w  = (const float*)d_in[14];
    const float* fc2_b  = (const float*)d_in[15];
    float* out = (float*)d_out;

    __bf16* W1ah  = (__bf16*)d_ws;                    // 163,840 bf16
    __bf16* W1al  = W1ah + 163840;                    // 163,840 bf16
    float*  Zpart = (float*)(W1al + 163840);          // 2*NGRP*2048 fp32 = 16 MB
    int*    cnt   = (int*)(Zpart + (size_t)2 * NGRP * 2048);  // NGRP ints

    hipLaunchKernelGGL(w1_prep, dim3(80), dim3(256), 0, stream,
                       fc1_w, W1ah, W1al, cnt);

    hipLaunchKernelGGL(lstm5_mfma, dim3(NGRP, 2), dim3(256), 0, stream,
                       accel, gyro, aWih0, aWihR, aWhh, aBih, aBhh,
                       gWih0, gWihR, gWhh, gBih, gBhh,
                       W1ah, W1al, Zpart, cnt, fc1_b, fc2_w, fc2_b, out);
}